// Round 2
// baseline (664.104 us; speedup 1.0000x reference)
//
#include <hip/hip_runtime.h>

// GwcVolume: group-wise correlation cost volume. FP32 in / FP32 out.
// B=1, F=320, G=40 groups, C=8 ch/group, H=128, W=256, D=48 disparities.
// lr[g,d,h,w] = (w>=d) ? mean_c L[g,c,h,w]*R[g,c,h,w-d] : 0
// rl[g,d,h,w] = lr row rotated left by d (masked head lands on rl's zero tail).
//
// Round-2: h-major sweep, barrier-free (write-stream locality, take 2).
// Baseline (573us total, kernel ~254us ~= 2.3 TB/s eff.): wave = (g,h), loops
// d -> 96 one-shot 1KB write islands at 128KB stride per wave; ~8K live
// islands device-wide -> HBM row thrash (fill on same buffer: 6.33 TB/s).
// Round-1 (604us): h-strip with SHARED R row needed 2 barriers/row + vmcnt
// drain -> serialized; streams only 8KB. Falsified the implementation, not
// the theory.
// This round: identical compute core to baseline (private 8KB R-row in LDS
// per wave, L quads in regs, 2 LDS reads/ch amortized over the 4-d batch,
// rl = rotation scatter), NO barriers (LDS wave-private). Only the loop
// order changes: block = (g, 4d-batch, 64-row half); wave wv sweeps rows
// h0+4k+wv. Per block: 8 output streams (4d x 2vol) advance sequentially
// over 64KB with a 4KB-coherent 4-wave front. Grid 960 = 3.75 blocks/CU ->
// all resident, 15 waves/CU latency hiding (baseline regime). 12x row
// re-reads served by L3 (84MB input).

#define G_     40
#define CPG    8
#define H_     128
#define W_     256
#define HW_    (H_ * W_)
#define HSTRIP 64

__global__ __launch_bounds__(256, 4)
void gwc_volume_kernel(const float* __restrict__ Lp,
                       const float* __restrict__ Rp,
                       const int* __restrict__ bins,
                       float* __restrict__ out,
                       int D)
{
    __shared__ float Rlds[4 * CPG * W_];   // 32 KB: per-wave private right row

    const int tid = threadIdx.x;
    const int wv  = tid >> 6;          // wave 0..3
    const int ln  = tid & 63;
    const int w4  = ln << 2;           // this lane's 4 w positions

    // block -> (g, db, h-half), XCD-chunked bijective remap (960 % 8 == 0).
    // Chunking keeps each XCD on ~5 groups -> input rows re-served from its L2.
    const int nD  = D >> 2;            // 12 four-d batches
    const int nHf = H_ / HSTRIP;       // 2
    int bx = blockIdx.x;
    const int cpx = (G_ * nD * nHf) >> 3;   // 120 blocks per XCD
    bx = (bx & 7) * cpx + (bx >> 3);

    const int g  = bx / (nD * nHf);
    const int r0 = bx - g * (nD * nHf);
    const int db = r0 / nHf;
    const int h0 = (r0 - db * nHf) * HSTRIP;

    const int di0 = db * 4;            // block's disparity batch (uniform)
    const int d0  = bins[di0];         // bins = arange -> d0 multiple of 4

    // Loop-invariant LDS window indices (d0 % 4 == 0 keeps b128 alignment;
    // clamped reads are only consumed where the w>=d mask zeroes the result).
    const int base = w4 - d0;
    const int ihi  = (base     < 0) ? 0 : base;
    const int ilo  = (base - 4 < 0) ? 0 : base - 4;

    float* Rw = &Rlds[wv * CPG * W_];
    float* out_rl = out + (size_t)G_ * D * HW_;
    const size_t gch = (size_t)(g * CPG) * HW_;
    const size_t ob0 = (size_t)(g * D + di0) * HW_;

    #pragma unroll 1
    for (int k = 0; k < HSTRIP / 4; ++k) {
        const int h = h0 + (k << 2) + wv;          // 4-wave coherent row front
        const size_t in_row = gch + (size_t)h * W_;

        // Stage this row: R -> private LDS, L -> regs (pre-scaled by 1/C).
        // No barrier: same-wave ds_write -> ds_read ordered via lgkmcnt.
        float4 lf[CPG];
        #pragma unroll
        for (int c = 0; c < CPG; ++c) {
            float4 rv = *(const float4*)(Rp + in_row + (size_t)c * HW_ + w4);
            float4 lv = *(const float4*)(Lp + in_row + (size_t)c * HW_ + w4);
            *(float4*)(&Rw[c * W_ + w4]) = rv;
            lf[c] = make_float4(lv.x * 0.125f, lv.y * 0.125f,
                                lv.z * 0.125f, lv.w * 0.125f);
        }

        float4 a0 = make_float4(0.f, 0.f, 0.f, 0.f);
        float4 a1 = a0, a2 = a0, a3 = a0;
        #pragma unroll
        for (int c = 0; c < CPG; ++c) {
            const float* rr  = &Rw[c * W_];
            float4 rlo = *(const float4*)(rr + ilo);
            float4 rhi = *(const float4*)(rr + ihi);
            float4 lc  = lf[c];
            // d = d0+0 : R indices w4+j-d0 -> rhi.xyzw
            a0.x = fmaf(lc.x, rhi.x, a0.x); a0.y = fmaf(lc.y, rhi.y, a0.y);
            a0.z = fmaf(lc.z, rhi.z, a0.z); a0.w = fmaf(lc.w, rhi.w, a0.w);
            // d = d0+1
            a1.x = fmaf(lc.x, rlo.w, a1.x); a1.y = fmaf(lc.y, rhi.x, a1.y);
            a1.z = fmaf(lc.z, rhi.y, a1.z); a1.w = fmaf(lc.w, rhi.z, a1.w);
            // d = d0+2
            a2.x = fmaf(lc.x, rlo.z, a2.x); a2.y = fmaf(lc.y, rlo.w, a2.y);
            a2.z = fmaf(lc.z, rhi.x, a2.z); a2.w = fmaf(lc.w, rhi.y, a2.w);
            // d = d0+3
            a3.x = fmaf(lc.x, rlo.y, a3.x); a3.y = fmaf(lc.y, rlo.z, a3.y);
            a3.z = fmaf(lc.z, rlo.w, a3.z); a3.w = fmaf(lc.w, rhi.x, a3.w);
        }

        const size_t orow = ob0 + (size_t)h * W_;
        float4 av[4] = {a0, a1, a2, a3};
        #pragma unroll
        for (int dd = 0; dd < 4; ++dd) {
            const int d = d0 + dd;
            float4 a = av[dd];
            float4 v;
            v.x = (w4 + 0 >= d) ? a.x : 0.f;
            v.y = (w4 + 1 >= d) ? a.y : 0.f;
            v.z = (w4 + 2 >= d) ? a.z : 0.f;
            v.w = (w4 + 3 >= d) ? a.w : 0.f;

            const size_t o = orow + (size_t)dd * HW_;
            *(float4*)(out + o + w4) = v;            // lr: aligned 16B

            // rl row = lr row rotated left by d (masked head -> zero tail).
            float* ro = out_rl + o;
            ro[(w4 + 0 - d) & (W_ - 1)] = v.x;
            ro[(w4 + 1 - d) & (W_ - 1)] = v.y;
            ro[(w4 + 2 - d) & (W_ - 1)] = v.z;
            ro[(w4 + 3 - d) & (W_ - 1)] = v.w;
        }
    }
}

extern "C" void kernel_launch(void* const* d_in, const int* in_sizes, int n_in,
                              void* d_out, int out_size, void* d_ws, size_t ws_size,
                              hipStream_t stream) {
    const float* L  = (const float*)d_in[0];
    const float* R  = (const float*)d_in[1];
    const int* bins = (const int*)d_in[2];
    float* out      = (float*)d_out;
    const int D = in_sizes[2];                              // 48
    const int blocks = G_ * (D >> 2) * (H_ / HSTRIP);       // 40*12*2 = 960
    gwc_volume_kernel<<<blocks, 256, 0, stream>>>(L, R, bins, out, D);
}

// Round 3
// 552.505 us; speedup vs baseline: 1.2020x; 1.2020x over previous
//
#include <hip/hip_runtime.h>

// GwcVolume: group-wise correlation cost volume. FP32 in / FP32 out.
// B=1, F=320, G=40 groups, C=8 ch/group, H=128, W=256, D=48 disparities.
// lr[g,d,h,w] = (w>=d) ? mean_c L[g,c,h,w]*R[g,c,h,w-d] : 0
// rl[g,d,h,w] = lr row rotated left by d (masked head lands on rl's zero tail).
//
// Round-3: baseline structure (d-major, best so far at 573us total), ONE
// change: rl is rotated IN REGISTERS (4 ds_bpermute per dd) and stored as an
// aligned dwordx4 burst, replacing the 16B-strided scalar scatter.
// Evidence trail:
//  r1 (h-strip + shared LDS + barriers): 604us  -> barriers serialize.
//  r2 (h-major, barrier-free, long write streams): 664us -> stream length
//     is NOT the bottleneck; 12x input re-read cost ~+90us. Theory dead.
//  New theory: rl scalar scatter (4B valid per 16B, 4 instrs covering each
//  64B sector) amplifies sector ops ~4x and defeats L2 write-merge ->
//  ~252MB of rl costs ~3-4x its bytes at HBM. Arithmetic:
//  (252lr+84in)@6.3 + 252rl@1.6 ~= 213us ~= observed kernel ~254us, while
//  all CU-pipe models give <20us. Rotation by d: d0%4==0 so d&3==dd is
//  compile-time and lane-shift k=d0>>2 is wave-uniform -> exactly 4 shfl
//  (conflict-free rotation) + static component naming per dd; lane-wrap
//  pulls the masked-zero head onto rl's zero tail, no extra mask.

#define G_   40
#define CPG  8
#define H_   128
#define W_   256
#define HW_  (H_ * W_)

__global__ __launch_bounds__(256, 4)
void gwc_volume_kernel(const float* __restrict__ Lp,
                       const float* __restrict__ Rp,
                       const int* __restrict__ bins,
                       float* __restrict__ out,
                       int D)
{
    __shared__ float Rlds[4 * CPG * W_];   // 32 KB: per-wave right row
    __shared__ int   bins_s[64];

    const int tid = threadIdx.x;
    const int wv  = tid >> 6;        // wave 0..3
    const int ln  = tid & 63;        // lane 0..63
    const int w4  = ln << 2;         // this lane's 4 w positions: w4..w4+3

    const int row = blockIdx.x * 4 + wv;   // 0..5119
    const int g   = row >> 7;              // / H_
    const int h   = row & (H_ - 1);

    if (tid < D) bins_s[tid] = bins[tid];

    const size_t in_row = (size_t)(g * CPG) * HW_ + (size_t)h * W_;

    // Left row -> registers (pre-scaled by 1/C); right row -> LDS.
    float4 lf[CPG];
    float* Rw = &Rlds[wv * CPG * W_];
    #pragma unroll
    for (int c = 0; c < CPG; ++c) {
        float4 lv = *(const float4*)(Lp + in_row + (size_t)c * HW_ + w4);
        float4 rv = *(const float4*)(Rp + in_row + (size_t)c * HW_ + w4);
        lf[c] = make_float4(lv.x * 0.125f, lv.y * 0.125f,
                            lv.z * 0.125f, lv.w * 0.125f);
        *(float4*)(&Rw[c * W_ + w4]) = rv;
    }
    __syncthreads();

    float* out_lr = out;
    float* out_rl = out + (size_t)G_ * D * HW_;
    const size_t obase = (size_t)g * D * HW_ + (size_t)h * W_;

    #pragma unroll 1
    for (int di0 = 0; di0 < D; di0 += 4) {
        const int d0   = bins_s[di0];
        const int base = w4 - d0;
        const int ihi  = (base     < 0) ? 0 : base;
        const int ilo  = (base - 4 < 0) ? 0 : base - 4;

        float4 a0 = make_float4(0.f, 0.f, 0.f, 0.f);
        float4 a1 = a0, a2 = a0, a3 = a0;

        #pragma unroll
        for (int c = 0; c < CPG; ++c) {
            const float* rr  = &Rw[c * W_];
            float4 rlo = *(const float4*)(rr + ilo);
            float4 rhi = *(const float4*)(rr + ihi);
            float4 lc  = lf[c];
            // d = d0+0 : R indices w4+j-d0 -> rhi.xyzw
            a0.x = fmaf(lc.x, rhi.x, a0.x); a0.y = fmaf(lc.y, rhi.y, a0.y);
            a0.z = fmaf(lc.z, rhi.z, a0.z); a0.w = fmaf(lc.w, rhi.w, a0.w);
            // d = d0+1
            a1.x = fmaf(lc.x, rlo.w, a1.x); a1.y = fmaf(lc.y, rhi.x, a1.y);
            a1.z = fmaf(lc.z, rhi.y, a1.z); a1.w = fmaf(lc.w, rhi.z, a1.w);
            // d = d0+2
            a2.x = fmaf(lc.x, rlo.z, a2.x); a2.y = fmaf(lc.y, rlo.w, a2.y);
            a2.z = fmaf(lc.z, rhi.x, a2.z); a2.w = fmaf(lc.w, rhi.y, a2.w);
            // d = d0+3
            a3.x = fmaf(lc.x, rlo.y, a3.x); a3.y = fmaf(lc.y, rlo.z, a3.y);
            a3.z = fmaf(lc.z, rlo.w, a3.z); a3.w = fmaf(lc.w, rhi.x, a3.w);
        }

        // Rotation lane sources (wave-uniform shift k = d0/4).
        const int k  = d0 >> 2;
        const int s0 = (ln + k)     & 63;
        const int s1 = (ln + k + 1) & 63;

        float4 av[4] = {a0, a1, a2, a3};
        #pragma unroll
        for (int dd = 0; dd < 4; ++dd) {
            float4 a   = av[dd];
            const int di = di0 + dd;
            const int d  = d0 + dd;
            float4 v;
            v.x = (w4 + 0 >= d) ? a.x : 0.f;
            v.y = (w4 + 1 >= d) ? a.y : 0.f;
            v.z = (w4 + 2 >= d) ? a.z : 0.f;
            v.w = (w4 + 3 >= d) ? a.w : 0.f;

            const size_t o = obase + (size_t)di * HW_;
            *(float4*)(out_lr + o + w4) = v;             // lr: aligned 16B

            // rl[w'] = v[(w'+d) mod 256]: in-register rotation. With
            // d = 4k+dd, output comp j sources comp (j+dd)&3 of lane
            // s0 (if j+dd<4) else s1 — static naming per dd. Wrapped
            // lanes deliver the masked-zero lr head onto rl's zero tail.
            float4 r;
            if (dd == 0) {
                r.x = __shfl(v.x, s0); r.y = __shfl(v.y, s0);
                r.z = __shfl(v.z, s0); r.w = __shfl(v.w, s0);
            } else if (dd == 1) {
                r.x = __shfl(v.y, s0); r.y = __shfl(v.z, s0);
                r.z = __shfl(v.w, s0); r.w = __shfl(v.x, s1);
            } else if (dd == 2) {
                r.x = __shfl(v.z, s0); r.y = __shfl(v.w, s0);
                r.z = __shfl(v.x, s1); r.w = __shfl(v.y, s1);
            } else {
                r.x = __shfl(v.w, s0); r.y = __shfl(v.x, s1);
                r.z = __shfl(v.y, s1); r.w = __shfl(v.z, s1);
            }
            *(float4*)(out_rl + o + w4) = r;             // rl: aligned 16B
        }
    }
}

extern "C" void kernel_launch(void* const* d_in, const int* in_sizes, int n_in,
                              void* d_out, int out_size, void* d_ws, size_t ws_size,
                              hipStream_t stream) {
    const float* L  = (const float*)d_in[0];
    const float* R  = (const float*)d_in[1];
    const int* bins = (const int*)d_in[2];
    float* out      = (float*)d_out;
    const int D = in_sizes[2];                 // 48
    const int blocks = (G_ * H_) / 4;          // 1280 blocks x 256 threads
    gwc_volume_kernel<<<blocks, 256, 0, stream>>>(L, R, bins, out, D);
}